// Round 4
// baseline (526.568 us; speedup 1.0000x reference)
//
#include <hip/hip_runtime.h>
#include <math.h>

#define PI_D 3.14159265358979323846264338327950288

#define NPIX 128
#define NFFT 512
#define BATCH 64
#define EXSZ 512          // per-wave exchange region, float2 (XOR layout, no pad)
#define TSTR 130          // passBC staging tile column stride (float2)

__device__ __forceinline__ float2 cmulf(float2 a, float2 b) {
    return make_float2(a.x*b.x - a.y*b.y, a.x*b.y + a.y*b.x);
}
__device__ __forceinline__ float2 cadd(float2 a, float2 b) {
    return make_float2(a.x + b.x, a.y + b.y);
}
__device__ __forceinline__ float2 csub(float2 a, float2 b) {
    return make_float2(a.x - b.x, a.y - b.y);
}
// a * (b.x + i*SGN*b.y): SGN=-1 multiplies by conj(b)
template<int SGN>
__device__ __forceinline__ float2 cmul_sgn(float2 a, float2 b) {
    return make_float2(a.x*b.x - (float)SGN*a.y*b.y,
                       (float)SGN*a.x*b.y + a.y*b.x);
}

// wave-synchronous LDS: drain DS queue + stop compiler reordering.
#define WSYNC() __asm__ volatile("s_waitcnt lgkmcnt(0)" ::: "memory")

// conflict-free exchange address maps (bijective mod 16 per 16-lane group)
__device__ __forceinline__ int ex1w(int k, int l)           { return 64*k  + (l ^ (2*k)); }
__device__ __forceinline__ int ex1r(int k, int k2, int hi)  { return 64*k2 + ((hi + 8*k) ^ (2*k2)); }
__device__ __forceinline__ int ex2w(int k, int l)           { return 64*k  + (l ^ (8*k)); }
__device__ __forceinline__ int ex2r(int k, int k2, int hi)  { return 64*hi + ((k2 + 8*k) ^ (8*hi)); }

// ---------------------------------------------------------------------------
// in-register 8-point DFT. SGN=-1 forward; SGN=+1 unnormalized inverse.
// ---------------------------------------------------------------------------
template<int SGN>
__device__ __forceinline__ void dft8(float2* x)
{
    const float C = 0.70710678118654752440f;
    float2 t0 = cadd(x[0], x[4]), t4 = csub(x[0], x[4]);
    float2 t1 = cadd(x[1], x[5]), t5 = csub(x[1], x[5]);
    float2 t2 = cadd(x[2], x[6]), t6 = csub(x[2], x[6]);
    float2 t3 = cadd(x[3], x[7]), t7 = csub(x[3], x[7]);
    float2 u5 = make_float2(C*(t5.x - SGN*t5.y), C*(t5.y + SGN*t5.x));
    float2 u6 = make_float2((float)(-SGN)*t6.y, (float)SGN*t6.x);
    float2 u7 = make_float2(-C*(t7.x + SGN*t7.y), C*(SGN*t7.x - t7.y));
    float2 s0 = cadd(t0, t2), s2 = csub(t0, t2);
    float2 s1 = cadd(t1, t3), d13 = csub(t1, t3);
    float2 s3 = make_float2((float)(-SGN)*d13.y, (float)SGN*d13.x);
    x[0] = cadd(s0, s1); x[4] = csub(s0, s1);
    x[2] = cadd(s2, s3); x[6] = csub(s2, s3);
    float2 s4 = cadd(t4, u6), s6 = csub(t4, u6);
    float2 s5 = cadd(u5, u7), d57 = csub(u5, u7);
    float2 s7 = make_float2((float)(-SGN)*d57.y, (float)SGN*d57.x);
    x[1] = cadd(s4, s5); x[5] = csub(s4, s5);
    x[3] = cadd(s6, s7); x[7] = csub(s6, s7);
}

// per-lane twiddle tables: W1[k]=w512^{l k}, W2[k]=w64^{hi k} (positive angle)
__device__ __forceinline__ void make_tw(int l, float2* W1, float2* W2)
{
    float s1, c1, s2, c2;
    __sincosf(0.012271846303085129838f * (float)l,        &s1, &c1); // 2pi/512
    __sincosf(0.098174770424681038701f * (float)(l >> 3), &s2, &c2); // 2pi/64
    W1[1] = make_float2(c1, s1);
    W2[1] = make_float2(c2, s2);
#pragma unroll
    for (int k = 2; k < 8; ++k) {
        W1[k] = cmulf(W1[k-1], W1[1]);
        W2[k] = cmulf(W2[k-1], W2[1]);
    }
}

// ---------------------------------------------------------------------------
// 512-point FFT, one wave, 8 complex/lane, radix-8 x3, natural order both ends
// ---------------------------------------------------------------------------
__device__ __forceinline__ void fwd512(float2* x, float2* ex, int l,
                                       const float2* W1, const float2* W2)
{
    const int k2 = l & 7, hi = l >> 3;
    dft8<-1>(x);
#pragma unroll
    for (int k = 1; k < 8; ++k) x[k] = cmul_sgn<-1>(x[k], W1[k]);
    WSYNC();
#pragma unroll
    for (int k = 0; k < 8; ++k) ex[ex1w(k, l)] = x[k];
    WSYNC();
#pragma unroll
    for (int k = 0; k < 8; ++k) x[k] = ex[ex1r(k, k2, hi)];
    dft8<-1>(x);
#pragma unroll
    for (int k = 1; k < 8; ++k) x[k] = cmul_sgn<-1>(x[k], W2[k]);
    WSYNC();
#pragma unroll
    for (int k = 0; k < 8; ++k) ex[ex2w(k, l)] = x[k];
    WSYNC();
#pragma unroll
    for (int k = 0; k < 8; ++k) x[k] = ex[ex2r(k, k2, hi)];
    dft8<-1>(x);
}

__device__ __forceinline__ void inv512(float2* x, float2* ex, int l,
                                       const float2* W1, const float2* W2)
{
    const int k2 = l & 7, hi = l >> 3;
    dft8<1>(x);
    WSYNC();
#pragma unroll
    for (int k = 0; k < 8; ++k) ex[ex2r(k, k2, hi)] = x[k];
    WSYNC();
#pragma unroll
    for (int k = 0; k < 8; ++k) x[k] = ex[ex2w(k, l)];
#pragma unroll
    for (int k = 1; k < 8; ++k) x[k] = cmul_sgn<1>(x[k], W2[k]);
    dft8<1>(x);
    WSYNC();
#pragma unroll
    for (int k = 0; k < 8; ++k) ex[ex1r(k, k2, hi)] = x[k];
    WSYNC();
#pragma unroll
    for (int k = 0; k < 8; ++k) x[k] = ex[ex1w(k, l)];
#pragma unroll
    for (int k = 1; k < 8; ++k) x[k] = cmul_sgn<1>(x[k], W1[k]);
    dft8<1>(x);
}

// ---------------------------------------------------------------------------
// setup: H built in double precision via Stockham ping-pong (one-time cost)
// ---------------------------------------------------------------------------
__device__ __forceinline__ int fft512d(double2 (*b)[NFFT], int t, double isign, int cur)
{
    for (int st = 0; st < 9; ++st) {
        const int s = 1 << st;
        const int p = t >> st;
        const int q = t & (s - 1);
        const int m = 256 >> st;
        const double2 a = b[cur][q + s*p];
        const double2 c = b[cur][q + s*(p + m)];
        double sw, cw;
        sincos(isign * (-PI_D/256.0) * (double)(p << st), &sw, &cw);
        const double2 dif = make_double2(a.x - c.x, a.y - c.y);
        b[cur^1][q + 2*s*p]     = make_double2(a.x + c.x, a.y + c.y);
        b[cur^1][q + 2*s*p + s] = make_double2(dif.x*cw - dif.y*sw,
                                               dif.x*sw + dif.y*cw);
        cur ^= 1;
        __syncthreads();
    }
    return cur;
}

__global__ __launch_bounds__(256) void k_build_w(double2* __restrict__ Wd)
{
    const double WLEN = 5.32e-07, PIX = 1.0e-4, DIST = 0.005;
    int idx = blockIdx.x*blockDim.x + threadIdx.x;   // 512*512 total
    int i = idx >> 9, j = idx & 511;
    double2 v = make_double2(0.0, 0.0);
    if (i < 257 && j < 257) {
        double cx = (double)(128 - i) * PIX;
        double cy = (double)(128 - j) * PIX;
        double r2 = cx*cx + cy*cy + DIST*DIST;
        double r  = sqrt(r2);
        double sc = PIX*PIX*DIST / r2;
        double re_a = 1.0/(2.0*PI_D*r);
        double im_a = -1.0/WLEN;
        double sp, cp;
        sincos(2.0*PI_D*r/WLEN, &sp, &cp);
        v.x = sc*(re_a*cp - im_a*sp);
        v.y = sc*(re_a*sp + im_a*cp);
    }
    Wd[idx] = v;
}

__global__ __launch_bounds__(256) void k_dfft_row(const double2* __restrict__ in,
                                                  double2* __restrict__ out)
{
    __shared__ double2 b[2][NFFT];
    int row = blockIdx.x, t = threadIdx.x;
    b[0][t]       = in[row*NFFT + t];
    b[0][t + 256] = in[row*NFFT + t + 256];
    __syncthreads();
    int cur = fft512d(b, t, 1.0, 0);
    out[row*NFFT + t]       = b[cur][t];
    out[row*NFFT + t + 256] = b[cur][t + 256];
}

// column FFT; Ht[kx*512 + ky] natural order, 1/512^2 folded in.
__global__ __launch_bounds__(256) void k_dfft_col_H(const double2* __restrict__ in,
                                                    float2* __restrict__ Ht)
{
    __shared__ double2 b[2][NFFT];
    int col = blockIdx.x, t = threadIdx.x;
    b[0][t]       = in[t*NFFT + col];
    b[0][t + 256] = in[(t + 256)*NFFT + col];
    __syncthreads();
    int cur = fft512d(b, t, 1.0, 0);
    const double scale = 1.0/(512.0*512.0);
    Ht[col*NFFT + t]       = make_float2((float)(b[cur][t].x*scale),
                                         (float)(b[cur][t].y*scale));
    Ht[col*NFFT + t + 256] = make_float2((float)(b[cur][t+256].x*scale),
                                         (float)(b[cur][t+256].y*scale));
}

// ---------------------------------------------------------------------------
// pass A0: init + first row FFT. block 256 = 4 waves = 4 rows, no barriers.
// ---------------------------------------------------------------------------
__global__ __launch_bounds__(256) void k_passA0(const float* __restrict__ x,
                                                float2* __restrict__ Abuf,
                                                float2* __restrict__ outc,
                                                float*  __restrict__ outr)
{
    __shared__ float2 ex_all[4*EXSZ];
    const int w = threadIdx.x >> 6, l = threadIdx.x & 63;
    const int row = blockIdx.x*4 + w, img = blockIdx.y;
    float2* ex = ex_all + w*EXSZ;
    float2 W1[8], W2[8];
    make_tw(l, W1, W2);

    const float* xr = x + (size_t)(img*NPIX + row)*NPIX;
    float2 v0 = make_float2(xr[l],      0.f);
    float2 v1 = make_float2(xr[l + 64], 0.f);
    size_t o = (size_t)(img*NPIX + row)*NPIX;
    if (outc) { outc[o + l] = v0; outc[o + 64 + l] = v1; }
    else      { outr[o + l] = v0.x; outr[o + 64 + l] = v1.x; }

    float2 X[8];
    X[0] = v0; X[1] = v1;
#pragma unroll
    for (int k = 2; k < 8; ++k) X[k] = make_float2(0.f, 0.f);
    fwd512(X, ex, l, W1, W2);
    float2* arow = Abuf + (size_t)(img*NPIX + row)*NFFT;
#pragma unroll
    for (int d = 0; d < 8; ++d) arow[l + 64*d] = X[d];
}

// ---------------------------------------------------------------------------
// pass BC: 8 columns/block (512 thr = 8 waves, 1 col each). Coalesced tile
// staging in LDS; per-wave register FFTs; H natural order.
// ---------------------------------------------------------------------------
__global__ __launch_bounds__(512) void k_passBC(float2* __restrict__ Abuf,
                                                const float2* __restrict__ Ht)
{
    __shared__ float2 T[8*TSTR];        // 8320 B staging
    __shared__ float2 ex_all[8*EXSZ];   // 32768 B exchange
    const int t = threadIdx.x;
    const int w = t >> 6, l = t & 63;
    const int img = blockIdx.x, c0 = blockIdx.y*8;
    float2* base = Abuf + (size_t)img*NPIX*NFFT;
    float2 W1[8], W2[8];
    make_tw(l, W1, W2);

    // coalesced tile load: (128 rows x 8 cols)
#pragma unroll
    for (int i = 0; i < 2; ++i) {
        int idx = t + 512*i;
        int cc = idx & 7, r = idx >> 3;
        T[cc*TSTR + r] = base[r*NFFT + c0 + cc];
    }
    __syncthreads();

    float2* ex = ex_all + w*EXSZ;
    float2 X[8];
    X[0] = T[w*TSTR + l];
    X[1] = T[w*TSTR + l + 64];
#pragma unroll
    for (int k = 2; k < 8; ++k) X[k] = make_float2(0.f, 0.f);

    fwd512(X, ex, l, W1, W2);
    const float2* Hrow = Ht + (size_t)(c0 + w)*NFFT;
#pragma unroll
    for (int d = 0; d < 8; ++d) X[d] = cmulf(X[d], Hrow[l + 64*d]);
    inv512(X, ex, l, W1, W2);

    // keep spatial rows 128..255 (regs 2,3)
    T[w*TSTR + l]      = X[2];
    T[w*TSTR + l + 64] = X[3];
    __syncthreads();

#pragma unroll
    for (int i = 0; i < 2; ++i) {
        int idx = t + 512*i;
        int cc = idx & 7, r = idx >> 3;
        base[r*NFFT + c0 + cc] = T[cc*TSTR + r];
    }
}

// ---------------------------------------------------------------------------
// pass DA: row IFFT + crop + mask + output, then forward row FFT. No barriers.
// ---------------------------------------------------------------------------
__global__ __launch_bounds__(256) void k_passDA(float2* __restrict__ Abuf,
                                                const float* __restrict__ phases,
                                                float2* __restrict__ outc,
                                                float*  __restrict__ outr,
                                                int layer)
{
    __shared__ float2 ex_all[4*EXSZ];
    const int w = threadIdx.x >> 6, l = threadIdx.x & 63;
    const int row = blockIdx.x*4 + w, img = blockIdx.y;
    float2* ex = ex_all + w*EXSZ;
    float2 W1[8], W2[8];
    make_tw(l, W1, W2);

    float2* arow = Abuf + (size_t)(img*NPIX + row)*NFFT;
    float2 X[8];
#pragma unroll
    for (int d = 0; d < 8; ++d) X[d] = arow[l + 64*d];
    inv512(X, ex, l, W1, W2);

    // crop cols 128..255 -> j = l (reg2), j = 64+l (reg3); apply mask
    const float* ph = phases + layer*4096 + (row >> 1)*64;
    float p0 = ph[(l >> 1)];
    float p1 = ph[32 + (l >> 1)];
    float cp0 = 6.2831853071795864769f * (1.f/(1.f + __expf(-p0)));
    float cp1 = 6.2831853071795864769f * (1.f/(1.f + __expf(-p1)));
    float s0, c0s, s1, c1s;
    __sincosf(cp0, &s0, &c0s);
    __sincosf(cp1, &s1, &c1s);
    float2 v0 = cmulf(X[2], make_float2(c0s, s0));
    float2 v1 = cmulf(X[3], make_float2(c1s, s1));

    size_t o = (size_t)(img*NPIX + row)*NPIX;
    if (outc) { outc[o + l] = v0; outc[o + 64 + l] = v1; }
    else      { outr[o + l] = v0.x; outr[o + 64 + l] = v1.x; }

    X[0] = v0; X[1] = v1;
#pragma unroll
    for (int k = 2; k < 8; ++k) X[k] = make_float2(0.f, 0.f);
    fwd512(X, ex, l, W1, W2);
#pragma unroll
    for (int d = 0; d < 8; ++d) arow[l + 64*d] = X[d];
}

// ---------------------------------------------------------------------------
// pass D last: row IFFT + crop + output + |.|^2. No barriers.
// ---------------------------------------------------------------------------
__global__ __launch_bounds__(256) void k_passDlast(const float2* __restrict__ Abuf,
                                                   float2* __restrict__ outc,
                                                   float*  __restrict__ outr,
                                                   float*  __restrict__ outabs)
{
    __shared__ float2 ex_all[4*EXSZ];
    const int w = threadIdx.x >> 6, l = threadIdx.x & 63;
    const int row = blockIdx.x*4 + w, img = blockIdx.y;
    float2* ex = ex_all + w*EXSZ;
    float2 W1[8], W2[8];
    make_tw(l, W1, W2);

    const float2* arow = Abuf + (size_t)(img*NPIX + row)*NFFT;
    float2 X[8];
#pragma unroll
    for (int d = 0; d < 8; ++d) X[d] = arow[l + 64*d];
    inv512(X, ex, l, W1, W2);

    float2 v0 = X[2], v1 = X[3];
    size_t o = (size_t)(img*NPIX + row)*NPIX;
    if (outc) { outc[o + l] = v0; outc[o + 64 + l] = v1; }
    else      { outr[o + l] = v0.x; outr[o + 64 + l] = v1.x; }
    outabs[o + l]      = v0.x*v0.x + v0.y*v0.y;
    outabs[o + 64 + l] = v1.x*v1.x + v1.y*v1.y;
}

// ---------------------------------------------------------------------------
extern "C" void kernel_launch(void* const* d_in, const int* in_sizes, int n_in,
                              void* d_out, int out_size, void* d_ws, size_t ws_size,
                              hipStream_t stream)
{
    const float* x      = (const float*)d_in[0];   // [64,128,128]
    const float* phases = (const float*)d_in[1];   // [5,64,64]
    float* out = (float*)d_out;
    char*  ws  = (char*)d_ws;

    // workspace layout
    float2* Ht   = (float2*)ws;                                   // 2 MB
    float2* Abuf = (float2*)(ws + (size_t)NFFT*NFFT*8);           // 33.5 MB
    // double temporaries for H construction alias the (not-yet-used) Abuf
    double2* Wd = (double2*)Abuf;                                 // 4 MB
    double2* Td = (double2*)((char*)Abuf + (size_t)NFFT*NFFT*16); // 4 MB

    const bool   inter   = (out_size >= 15728640);
    const size_t cstride = inter ? 2097152u : 1048576u;

    k_build_w   <<<1024, 256, 0, stream>>>(Wd);
    k_dfft_row  <<<NFFT, 256, 0, stream>>>(Wd, Td);
    k_dfft_col_H<<<NFFT, 256, 0, stream>>>(Td, Ht);

    {
        float* c1 = out + 1048576;
        k_passA0<<<dim3(NPIX/4, BATCH), 256, 0, stream>>>(
            x, Abuf,
            inter ? (float2*)c1 : nullptr,
            inter ? nullptr : c1);
    }

    for (int step = 0; step < 6; ++step) {
        k_passBC<<<dim3(BATCH, NFFT/8), 512, 0, stream>>>(Abuf, Ht);
        float* chunk = out + 1048576 + (size_t)(step + 1)*cstride;
        if (step < 5) {
            k_passDA<<<dim3(NPIX/4, BATCH), 256, 0, stream>>>(
                Abuf, phases,
                inter ? (float2*)chunk : nullptr,
                inter ? nullptr : chunk, step);
        } else {
            k_passDlast<<<dim3(NPIX/4, BATCH), 256, 0, stream>>>(
                Abuf,
                inter ? (float2*)chunk : nullptr,
                inter ? nullptr : chunk,
                out /* x_abs chunk0 */);
        }
    }
}

// Round 5
// 458.636 us; speedup vs baseline: 1.1481x; 1.1481x over previous
//
#include <hip/hip_runtime.h>
#include <math.h>

#define PI_D 3.14159265358979323846264338327950288

#define NPIX 128
#define NFFT 512
#define BATCH 64
#define EXSZ 512          // per-wave exchange region, float2 (XOR layout, no pad)
#define TSTR 130          // passBC staging tile column stride (float2)

__device__ __forceinline__ float2 cmulf(float2 a, float2 b) {
    return make_float2(a.x*b.x - a.y*b.y, a.x*b.y + a.y*b.x);
}
__device__ __forceinline__ float2 cadd(float2 a, float2 b) {
    return make_float2(a.x + b.x, a.y + b.y);
}
__device__ __forceinline__ float2 csub(float2 a, float2 b) {
    return make_float2(a.x - b.x, a.y - b.y);
}

// wave-synchronous LDS: drain DS queue + stop compiler reordering.
#define WSYNC() __asm__ volatile("s_waitcnt lgkmcnt(0)" ::: "memory")

// conflict-free exchange address maps (bijective mod 16 per 16-lane group)
__device__ __forceinline__ int ex1w(int k, int l)           { return 64*k  + (l ^ (2*k)); }
__device__ __forceinline__ int ex1r(int k, int k2, int hi)  { return 64*k2 + ((hi + 8*k) ^ (2*k2)); }
__device__ __forceinline__ int ex2w(int k, int l)           { return 64*k  + (l ^ (8*k)); }
__device__ __forceinline__ int ex2r(int k, int k2, int hi)  { return 64*hi + ((k2 + 8*k) ^ (8*hi)); }

// ---------------------------------------------------------------------------
// in-register 8-point DFT. SGN=-1 forward; SGN=+1 unnormalized inverse.
// ---------------------------------------------------------------------------
template<int SGN>
__device__ __forceinline__ void dft8(float2* x)
{
    const float C = 0.70710678118654752440f;
    float2 t0 = cadd(x[0], x[4]), t4 = csub(x[0], x[4]);
    float2 t1 = cadd(x[1], x[5]), t5 = csub(x[1], x[5]);
    float2 t2 = cadd(x[2], x[6]), t6 = csub(x[2], x[6]);
    float2 t3 = cadd(x[3], x[7]), t7 = csub(x[3], x[7]);
    float2 u5 = make_float2(C*(t5.x - SGN*t5.y), C*(t5.y + SGN*t5.x));
    float2 u6 = make_float2((float)(-SGN)*t6.y, (float)SGN*t6.x);
    float2 u7 = make_float2(-C*(t7.x + SGN*t7.y), C*(SGN*t7.x - t7.y));
    float2 s0 = cadd(t0, t2), s2 = csub(t0, t2);
    float2 s1 = cadd(t1, t3), d13 = csub(t1, t3);
    float2 s3 = make_float2((float)(-SGN)*d13.y, (float)SGN*d13.x);
    x[0] = cadd(s0, s1); x[4] = csub(s0, s1);
    x[2] = cadd(s2, s3); x[6] = csub(s2, s3);
    float2 s4 = cadd(t4, u6), s6 = csub(t4, u6);
    float2 s5 = cadd(u5, u7), d57 = csub(u5, u7);
    float2 s7 = make_float2((float)(-SGN)*d57.y, (float)SGN*d57.x);
    x[1] = cadd(s4, s5); x[5] = csub(s4, s5);
    x[3] = cadd(s6, s7); x[7] = csub(s6, s7);
}

// apply x[k] *= base^k for k=1..7 (6-cmul chain, low VGPR)
__device__ __forceinline__ void twpow(float2* x, float2 base)
{
    float2 w = base;
#pragma unroll
    for (int k = 1; k < 8; ++k) {
        x[k] = cmulf(x[k], w);
        w = cmulf(w, base);
    }
}

// per-lane twiddle bases (4 VGPRs total). b1 = w512^{-l}, b2 = w64^{-hi}
// (forward sign); conjugate for inverse.
__device__ __forceinline__ void make_bases(int l, float2* b1, float2* b2)
{
    float s1, c1, s2, c2;
    __sincosf(0.012271846303085129838f * (float)l,        &s1, &c1); // 2pi/512
    __sincosf(0.098174770424681038701f * (float)(l >> 3), &s2, &c2); // 2pi/64
    *b1 = make_float2(c1, s1);
    *b2 = make_float2(c2, s2);
}

// ---------------------------------------------------------------------------
// 512-point FFT, one wave, 8 complex/lane, radix-8 x3, natural order both ends
// bases passed with FORWARD sign already applied (conj for inverse at callsite)
// ---------------------------------------------------------------------------
__device__ __forceinline__ void fwd512(float2* x, float2* ex, int l,
                                       float2 b1, float2 b2)
{
    const int k2 = l & 7, hi = l >> 3;
    dft8<-1>(x);
    twpow(x, b1);
    WSYNC();
#pragma unroll
    for (int k = 0; k < 8; ++k) ex[ex1w(k, l)] = x[k];
    WSYNC();
#pragma unroll
    for (int k = 0; k < 8; ++k) x[k] = ex[ex1r(k, k2, hi)];
    dft8<-1>(x);
    twpow(x, b2);
    WSYNC();
#pragma unroll
    for (int k = 0; k < 8; ++k) ex[ex2w(k, l)] = x[k];
    WSYNC();
#pragma unroll
    for (int k = 0; k < 8; ++k) x[k] = ex[ex2r(k, k2, hi)];
    dft8<-1>(x);
}

__device__ __forceinline__ void inv512(float2* x, float2* ex, int l,
                                       float2 b1, float2 b2)
{
    const int k2 = l & 7, hi = l >> 3;
    dft8<1>(x);
    WSYNC();
#pragma unroll
    for (int k = 0; k < 8; ++k) ex[ex2r(k, k2, hi)] = x[k];
    WSYNC();
#pragma unroll
    for (int k = 0; k < 8; ++k) x[k] = ex[ex2w(k, l)];
    twpow(x, b2);
    dft8<1>(x);
    WSYNC();
#pragma unroll
    for (int k = 0; k < 8; ++k) ex[ex1r(k, k2, hi)] = x[k];
    WSYNC();
#pragma unroll
    for (int k = 0; k < 8; ++k) x[k] = ex[ex1w(k, l)];
    twpow(x, b1);
    dft8<1>(x);
}

// ---------------------------------------------------------------------------
// setup: H built in double precision via Stockham ping-pong (one-time cost)
// ---------------------------------------------------------------------------
__device__ __forceinline__ int fft512d(double2 (*b)[NFFT], int t, double isign, int cur)
{
    for (int st = 0; st < 9; ++st) {
        const int s = 1 << st;
        const int p = t >> st;
        const int q = t & (s - 1);
        const int m = 256 >> st;
        const double2 a = b[cur][q + s*p];
        const double2 c = b[cur][q + s*(p + m)];
        double sw, cw;
        sincos(isign * (-PI_D/256.0) * (double)(p << st), &sw, &cw);
        const double2 dif = make_double2(a.x - c.x, a.y - c.y);
        b[cur^1][q + 2*s*p]     = make_double2(a.x + c.x, a.y + c.y);
        b[cur^1][q + 2*s*p + s] = make_double2(dif.x*cw - dif.y*sw,
                                               dif.x*sw + dif.y*cw);
        cur ^= 1;
        __syncthreads();
    }
    return cur;
}

__global__ __launch_bounds__(256) void k_build_w(double2* __restrict__ Wd)
{
    const double WLEN = 5.32e-07, PIX = 1.0e-4, DIST = 0.005;
    int idx = blockIdx.x*blockDim.x + threadIdx.x;   // 512*512 total
    int i = idx >> 9, j = idx & 511;
    double2 v = make_double2(0.0, 0.0);
    if (i < 257 && j < 257) {
        double cx = (double)(128 - i) * PIX;
        double cy = (double)(128 - j) * PIX;
        double r2 = cx*cx + cy*cy + DIST*DIST;
        double r  = sqrt(r2);
        double sc = PIX*PIX*DIST / r2;
        double re_a = 1.0/(2.0*PI_D*r);
        double im_a = -1.0/WLEN;
        double sp, cp;
        sincos(2.0*PI_D*r/WLEN, &sp, &cp);
        v.x = sc*(re_a*cp - im_a*sp);
        v.y = sc*(re_a*sp + im_a*cp);
    }
    Wd[idx] = v;
}

__global__ __launch_bounds__(256) void k_dfft_row(const double2* __restrict__ in,
                                                  double2* __restrict__ out)
{
    __shared__ double2 b[2][NFFT];
    int row = blockIdx.x, t = threadIdx.x;
    b[0][t]       = in[row*NFFT + t];
    b[0][t + 256] = in[row*NFFT + t + 256];
    __syncthreads();
    int cur = fft512d(b, t, 1.0, 0);
    out[row*NFFT + t]       = b[cur][t];
    out[row*NFFT + t + 256] = b[cur][t + 256];
}

// column FFT; Ht[kx*512 + ky] natural order, 1/512^2 folded in.
__global__ __launch_bounds__(256) void k_dfft_col_H(const double2* __restrict__ in,
                                                    float2* __restrict__ Ht)
{
    __shared__ double2 b[2][NFFT];
    int col = blockIdx.x, t = threadIdx.x;
    b[0][t]       = in[t*NFFT + col];
    b[0][t + 256] = in[(t + 256)*NFFT + col];
    __syncthreads();
    int cur = fft512d(b, t, 1.0, 0);
    const double scale = 1.0/(512.0*512.0);
    Ht[col*NFFT + t]       = make_float2((float)(b[cur][t].x*scale),
                                         (float)(b[cur][t].y*scale));
    Ht[col*NFFT + t + 256] = make_float2((float)(b[cur][t+256].x*scale),
                                         (float)(b[cur][t+256].y*scale));
}

// ---------------------------------------------------------------------------
// pass A0: init + first row FFT. block 256 = 4 waves = 4 rows, no barriers.
// ---------------------------------------------------------------------------
__global__ __launch_bounds__(256) void k_passA0(const float* __restrict__ x,
                                                float2* __restrict__ Abuf,
                                                float2* __restrict__ outc,
                                                float*  __restrict__ outr)
{
    __shared__ float2 ex_all[4*EXSZ];
    const int w = threadIdx.x >> 6, l = threadIdx.x & 63;
    const int row = blockIdx.x*4 + w, img = blockIdx.y;
    float2* ex = ex_all + w*EXSZ;
    float2 b1, b2;
    make_bases(l, &b1, &b2);

    const float* xr = x + (size_t)(img*NPIX + row)*NPIX;
    float2 v0 = make_float2(xr[l],      0.f);
    float2 v1 = make_float2(xr[l + 64], 0.f);
    size_t o = (size_t)(img*NPIX + row)*NPIX;
    if (outc) { outc[o + l] = v0; outc[o + 64 + l] = v1; }
    else      { outr[o + l] = v0.x; outr[o + 64 + l] = v1.x; }

    float2 X[8];
    X[0] = v0; X[1] = v1;
#pragma unroll
    for (int k = 2; k < 8; ++k) X[k] = make_float2(0.f, 0.f);
    fwd512(X, ex, l, make_float2(b1.x, -b1.y), make_float2(b2.x, -b2.y));
    float2* arow = Abuf + (size_t)(img*NPIX + row)*NFFT;
#pragma unroll
    for (int d = 0; d < 8; ++d) arow[l + 64*d] = X[d];
}

// ---------------------------------------------------------------------------
// pass BC: 8 columns/block (512 thr = 8 waves, 1 col each). Coalesced tile
// staging in LDS; per-wave register FFTs; H natural order.
// ---------------------------------------------------------------------------
__global__ __launch_bounds__(512) void k_passBC(float2* __restrict__ Abuf,
                                                const float2* __restrict__ Ht)
{
    __shared__ float2 T[8*TSTR];        // 8320 B staging
    __shared__ float2 ex_all[8*EXSZ];   // 32768 B exchange
    const int t = threadIdx.x;
    const int w = t >> 6, l = t & 63;
    const int img = blockIdx.x, c0 = blockIdx.y*8;
    float2* base = Abuf + (size_t)img*NPIX*NFFT;
    float2 b1, b2;
    make_bases(l, &b1, &b2);

    // coalesced tile load: (128 rows x 8 cols)
#pragma unroll
    for (int i = 0; i < 2; ++i) {
        int idx = t + 512*i;
        int cc = idx & 7, r = idx >> 3;
        T[cc*TSTR + r] = base[r*NFFT + c0 + cc];
    }
    __syncthreads();

    float2* ex = ex_all + w*EXSZ;
    float2 X[8];
    X[0] = T[w*TSTR + l];
    X[1] = T[w*TSTR + l + 64];
#pragma unroll
    for (int k = 2; k < 8; ++k) X[k] = make_float2(0.f, 0.f);

    fwd512(X, ex, l, make_float2(b1.x, -b1.y), make_float2(b2.x, -b2.y));
    const float2* Hrow = Ht + (size_t)(c0 + w)*NFFT;
#pragma unroll
    for (int d = 0; d < 8; ++d) X[d] = cmulf(X[d], Hrow[l + 64*d]);
    inv512(X, ex, l, b1, b2);

    // keep spatial rows 128..255 (regs 2,3)
    T[w*TSTR + l]      = X[2];
    T[w*TSTR + l + 64] = X[3];
    __syncthreads();

#pragma unroll
    for (int i = 0; i < 2; ++i) {
        int idx = t + 512*i;
        int cc = idx & 7, r = idx >> 3;
        base[r*NFFT + c0 + cc] = T[cc*TSTR + r];
    }
}

// ---------------------------------------------------------------------------
// pass DA: row IFFT + crop + mask + output, then forward row FFT. No barriers.
// ---------------------------------------------------------------------------
__global__ __launch_bounds__(256) void k_passDA(float2* __restrict__ Abuf,
                                                const float* __restrict__ phases,
                                                float2* __restrict__ outc,
                                                float*  __restrict__ outr,
                                                int layer)
{
    __shared__ float2 ex_all[4*EXSZ];
    const int w = threadIdx.x >> 6, l = threadIdx.x & 63;
    const int row = blockIdx.x*4 + w, img = blockIdx.y;
    float2* ex = ex_all + w*EXSZ;
    float2 b1, b2;
    make_bases(l, &b1, &b2);

    float2* arow = Abuf + (size_t)(img*NPIX + row)*NFFT;
    float2 X[8];
#pragma unroll
    for (int d = 0; d < 8; ++d) X[d] = arow[l + 64*d];
    inv512(X, ex, l, b1, b2);

    // crop cols 128..255 -> j = l (reg2), j = 64+l (reg3); apply mask
    const float* ph = phases + layer*4096 + (row >> 1)*64;
    float p0 = ph[(l >> 1)];
    float p1 = ph[32 + (l >> 1)];
    float cp0 = 6.2831853071795864769f * (1.f/(1.f + __expf(-p0)));
    float cp1 = 6.2831853071795864769f * (1.f/(1.f + __expf(-p1)));
    float s0, c0s, s1, c1s;
    __sincosf(cp0, &s0, &c0s);
    __sincosf(cp1, &s1, &c1s);
    float2 v0 = cmulf(X[2], make_float2(c0s, s0));
    float2 v1 = cmulf(X[3], make_float2(c1s, s1));

    size_t o = (size_t)(img*NPIX + row)*NPIX;
    if (outc) { outc[o + l] = v0; outc[o + 64 + l] = v1; }
    else      { outr[o + l] = v0.x; outr[o + 64 + l] = v1.x; }

    X[0] = v0; X[1] = v1;
#pragma unroll
    for (int k = 2; k < 8; ++k) X[k] = make_float2(0.f, 0.f);
    fwd512(X, ex, l, make_float2(b1.x, -b1.y), make_float2(b2.x, -b2.y));
#pragma unroll
    for (int d = 0; d < 8; ++d) arow[l + 64*d] = X[d];
}

// ---------------------------------------------------------------------------
// pass D last: row IFFT + crop + output + |.|^2. No barriers.
// ---------------------------------------------------------------------------
__global__ __launch_bounds__(256) void k_passDlast(const float2* __restrict__ Abuf,
                                                   float2* __restrict__ outc,
                                                   float*  __restrict__ outr,
                                                   float*  __restrict__ outabs)
{
    __shared__ float2 ex_all[4*EXSZ];
    const int w = threadIdx.x >> 6, l = threadIdx.x & 63;
    const int row = blockIdx.x*4 + w, img = blockIdx.y;
    float2* ex = ex_all + w*EXSZ;
    float2 b1, b2;
    make_bases(l, &b1, &b2);

    const float2* arow = Abuf + (size_t)(img*NPIX + row)*NFFT;
    float2 X[8];
#pragma unroll
    for (int d = 0; d < 8; ++d) X[d] = arow[l + 64*d];
    inv512(X, ex, l, b1, b2);

    float2 v0 = X[2], v1 = X[3];
    size_t o = (size_t)(img*NPIX + row)*NPIX;
    if (outc) { outc[o + l] = v0; outc[o + 64 + l] = v1; }
    else      { outr[o + l] = v0.x; outr[o + 64 + l] = v1.x; }
    outabs[o + l]      = v0.x*v0.x + v0.y*v0.y;
    outabs[o + 64 + l] = v1.x*v1.x + v1.y*v1.y;
}

// ---------------------------------------------------------------------------
extern "C" void kernel_launch(void* const* d_in, const int* in_sizes, int n_in,
                              void* d_out, int out_size, void* d_ws, size_t ws_size,
                              hipStream_t stream)
{
    const float* x      = (const float*)d_in[0];   // [64,128,128]
    const float* phases = (const float*)d_in[1];   // [5,64,64]
    float* out = (float*)d_out;
    char*  ws  = (char*)d_ws;

    // workspace layout
    float2* Ht   = (float2*)ws;                                   // 2 MB
    float2* Abuf = (float2*)(ws + (size_t)NFFT*NFFT*8);           // 33.5 MB
    // double temporaries for H construction alias the (not-yet-used) Abuf
    double2* Wd = (double2*)Abuf;                                 // 4 MB
    double2* Td = (double2*)((char*)Abuf + (size_t)NFFT*NFFT*16); // 4 MB

    const bool   inter   = (out_size >= 15728640);
    const size_t cstride = inter ? 2097152u : 1048576u;

    k_build_w   <<<1024, 256, 0, stream>>>(Wd);
    k_dfft_row  <<<NFFT, 256, 0, stream>>>(Wd, Td);
    k_dfft_col_H<<<NFFT, 256, 0, stream>>>(Td, Ht);

    {
        float* c1 = out + 1048576;
        k_passA0<<<dim3(NPIX/4, BATCH), 256, 0, stream>>>(
            x, Abuf,
            inter ? (float2*)c1 : nullptr,
            inter ? nullptr : c1);
    }

    for (int step = 0; step < 6; ++step) {
        k_passBC<<<dim3(BATCH, NFFT/8), 512, 0, stream>>>(Abuf, Ht);
        float* chunk = out + 1048576 + (size_t)(step + 1)*cstride;
        if (step < 5) {
            k_passDA<<<dim3(NPIX/4, BATCH), 256, 0, stream>>>(
                Abuf, phases,
                inter ? (float2*)chunk : nullptr,
                inter ? nullptr : chunk, step);
        } else {
            k_passDlast<<<dim3(NPIX/4, BATCH), 256, 0, stream>>>(
                Abuf,
                inter ? (float2*)chunk : nullptr,
                inter ? nullptr : chunk,
                out /* x_abs chunk0 */);
        }
    }
}